// Round 10
// baseline (995.835 us; speedup 1.0000x reference)
//
#include <hip/hip_runtime.h>

// ---------------------------------------------------------------------------
// GCN link predictor: 3x (GCNConv -> BN -> ReLU) -> GCNConv -> edge MLP decoder
//   - CSR build, atomic-minimized (R8): hist atomic RETURNS rank -> scatter is
//     atomic-free; deg derived from CSR segments; dinv folded into edge weight.
//   - BN stats (R9): two-stage atomic-free reduction. Stage 1: 512 blocks,
//     float4 loads, f64 partials via LDS tree. Stage 2: 128-thread reduce
//     fused with scale/shift finalize. (Old version: 196 blocks x 128 scalar
//     threads = 3.6% occupancy, 67 us/layer latency-bound.)
//   - Layer 1: aggregate raw x (32-dim) FIRST, then GEMM (conv commutes).
//     Layers 2-4: GEMM (fused BN+ReLU of prev layer in A-staging) ->
//     wave-per-node aggregation (no atomics, 4-deep ILP)
//   - GEMM: 64x64 tile, K chunked in BK=64 stages -> 32KB LDS
//   - Decoder: first MLP layer hoisted to node level; per-edge kernel =
//     gather+bias+relu -> 64x64 MLP2 -> dot, shuffle-reduced.
// LDS swizzle: c' = c ^ (((k>>2)&7)<<2) (see R4 notes).
// ---------------------------------------------------------------------------

#define BN_BLOCKS 512

__device__ __forceinline__ float frelu(float v) { return v > 0.f ? v : 0.f; }
__device__ __forceinline__ int swz(int k, int c) { return c ^ (((k >> 2) & 7) << 2); }

// rank[e] = arrival index of edge e within its destination bin (also builds hist)
__global__ void hist_rank_kernel(const int* __restrict__ col, int* __restrict__ hist,
                                 int* __restrict__ rank, int E) {
  int e = blockIdx.x * blockDim.x + threadIdx.x;
  if (e < E) rank[e] = atomicAdd(&hist[col[e]], 1);
}

// Single-block exclusive scan over hist[n] -> indptr[n+1]. 1024 threads.
__global__ void scan_kernel(const int* __restrict__ hist, int* __restrict__ indptr, int n) {
  __shared__ int wsum[16];
  __shared__ int carry_s;
  int t = threadIdx.x, lane = t & 63, w = t >> 6;
  if (t == 0) carry_s = 0;
  __syncthreads();
  for (int base = 0; base < n; base += 1024) {
    int i = base + t;
    int v = (i < n) ? hist[i] : 0;
    int incl = v;
#pragma unroll
    for (int off = 1; off < 64; off <<= 1) {
      int u = __shfl_up(incl, off);
      if (lane >= off) incl += u;
    }
    if (lane == 63) wsum[w] = incl;
    __syncthreads();
    int woff = 0;
    for (int q = 0; q < w; ++q) woff += wsum[q];
    int excl = carry_s + woff + (incl - v);
    if (i < n) indptr[i] = excl;
    __syncthreads();
    if (t == 1023) carry_s += woff + incl;  // chunk total
    __syncthreads();
  }
  if (threadIdx.x == 0) indptr[n] = carry_s;
}

// Atomic-free scatter: sedge[indptr[col]+rank] = { bitcast(row), ew }
__global__ void scatter_kernel(const int* __restrict__ row, const int* __restrict__ col,
                               const float* __restrict__ ew, const int* __restrict__ indptr,
                               const int* __restrict__ rank, float2* __restrict__ sedge, int E) {
  int e = blockIdx.x * blockDim.x + threadIdx.x;
  if (e < E) {
    int pos = indptr[col[e]] + rank[e];
    sedge[pos] = make_float2(__int_as_float(row[e]), ew[e]);
  }
}

// deg from CSR segments (no atomics): deg[i] = 1 (self) + sum ew; dinv = rsqrt
__global__ void deg_dinv_kernel(const float2* __restrict__ sedge, const int* __restrict__ indptr,
                                float* __restrict__ dinv, int n) {
  int i = blockIdx.x * blockDim.x + threadIdx.x;
  if (i >= n) return;
  int beg = indptr[i], end = indptr[i + 1];
  float s = 1.0f;  // self-loop weight
  for (int e = beg; e < end; ++e) s += sedge[e].y;
  dinv[i] = rsqrtf(s);
}

// Fold dinv[row] into the stored weight: sedge[p].y *= dinv[row_p]
__global__ void edgew_kernel(float2* __restrict__ sedge, const float* __restrict__ dinv, int E) {
  int p = blockIdx.x * blockDim.x + threadIdx.x;
  if (p < E) {
    float2 v = sedge[p];
    v.y *= dinv[__float_as_int(v.x)];
    sedge[p] = v;
  }
}

// C[n,F] = act(A)[n,K] @ W[K,F] (+bias).  64x64 tile, 256 threads, 4x4/thread.
// K chunked in BK<=64 stages -> 32KB LDS max. If ss != nullptr, A-staging
// applies relu(a*ss[k].x + ss[k].y) (fused BN+ReLU of the previous layer).
template <int K>
__global__ __launch_bounds__(256) void gemm_kernel(const float* __restrict__ A,
                                                   const float* __restrict__ W,
                                                   float* __restrict__ C, int n, int F,
                                                   const float2* __restrict__ ss,
                                                   const float* __restrict__ bias) {
  constexpr int BK = (K > 64) ? 64 : K;
  __shared__ float At[BK * 64];  // At[kk][swz(kk,r)]
  __shared__ float Wl[BK * 64];  // Wl[kk][c]
  int t = threadIdx.x;
  int r0 = blockIdx.x * 64, c0 = blockIdx.y * 64;
  int tx = t & 15, ty = t >> 4;
  float acc[4][4] = {};
  for (int k0 = 0; k0 < K; k0 += BK) {
    if (k0) __syncthreads();  // previous chunk's compute done before overwrite
    for (int e = t; e < 64 * BK; e += 256) {
      int r = e / BK, kk = e % BK;  // kk lane-fast: coalesced global read
      int k = k0 + kk;
      float v = (r0 + r < n) ? A[(size_t)(r0 + r) * K + k] : 0.f;
      if (ss) {
        float2 s = ss[k];
        v = frelu(fmaf(v, s.x, s.y));
      }
      At[kk * 64 + swz(kk, r)] = v;
    }
    for (int e = t; e < BK * 64; e += 256) {
      int kk = e >> 6, c = e & 63;
      Wl[e] = W[(size_t)(k0 + kk) * F + c0 + c];
    }
    __syncthreads();
#pragma unroll 8
    for (int kk = 0; kk < BK; ++kk) {
      float4 a4 = *(const float4*)&At[kk * 64 + swz(kk, ty * 4)];
      float4 b4 = *(const float4*)&Wl[kk * 64 + tx * 4];
      float a[4] = {a4.x, a4.y, a4.z, a4.w};
      float b[4] = {b4.x, b4.y, b4.z, b4.w};
#pragma unroll
      for (int i = 0; i < 4; ++i)
#pragma unroll
        for (int j = 0; j < 4; ++j) acc[i][j] = fmaf(a[i], b[j], acc[i][j]);
    }
  }
  float4 bv = make_float4(0.f, 0.f, 0.f, 0.f);
  if (bias) bv = *(const float4*)&bias[c0 + tx * 4];
#pragma unroll
  for (int i = 0; i < 4; ++i) {
    int r = r0 + ty * 4 + i;
    if (r < n) {
      float4 o = make_float4(acc[i][0] + bv.x, acc[i][1] + bv.y, acc[i][2] + bv.z,
                             acc[i][3] + bv.w);
      *(float4*)&C[(size_t)r * F + c0 + tx * 4] = o;
    }
  }
}

// P[n,128]: cols 0..63 = enc @ dw1[0:64,:], cols 64..127 = enc @ dw1[64:128,:]
__global__ __launch_bounds__(256) void pre_gemm_kernel(const float* __restrict__ enc,
                                                       const float* __restrict__ dw1,
                                                       float* __restrict__ P, int n) {
  __shared__ float At[64 * 64];
  __shared__ float Wl[64 * 64];
  int t = threadIdx.x;
  int r0 = blockIdx.x * 64;
  const float* W = dw1 + blockIdx.y * 4096;  // [64,64] half of dw1
  for (int e = t; e < 64 * 64; e += 256) {
    int r = e >> 6, k = e & 63;
    At[k * 64 + swz(k, r)] = (r0 + r < n) ? enc[(size_t)(r0 + r) * 64 + k] : 0.f;
  }
  for (int e = t; e < 4096; e += 256) Wl[e] = W[e];
  __syncthreads();
  int tx = t & 15, ty = t >> 4;
  float acc[4][4] = {};
#pragma unroll 8
  for (int k = 0; k < 64; ++k) {
    float4 a4 = *(const float4*)&At[k * 64 + swz(k, ty * 4)];
    float4 b4 = *(const float4*)&Wl[k * 64 + tx * 4];
    float a[4] = {a4.x, a4.y, a4.z, a4.w};
    float b[4] = {b4.x, b4.y, b4.z, b4.w};
#pragma unroll
    for (int i = 0; i < 4; ++i)
#pragma unroll
      for (int j = 0; j < 4; ++j) acc[i][j] = fmaf(a[i], b[j], acc[i][j]);
  }
#pragma unroll
  for (int i = 0; i < 4; ++i) {
    int r = r0 + ty * 4 + i;
    if (r < n) {
      float4 o = make_float4(acc[i][0], acc[i][1], acc[i][2], acc[i][3]);
      *(float4*)&P[(size_t)r * 128 + blockIdx.y * 64 + tx * 4] = o;
    }
  }
}

// Layer-1 aggregation on raw x [n,32]: 2 nodes per wave, 32 lanes each.
// sedge.y = dinv[row]*ew.  out[i,k] = dinv[i]*( sum_e w_e*x[row_e,k] + dinv[i]*x[i,k] )
__global__ void agg32_kernel(const float* __restrict__ x, const int* __restrict__ indptr,
                             const float2* __restrict__ sedge, const float* __restrict__ dinv,
                             float* __restrict__ out, int n) {
  int gid = blockIdx.x * blockDim.x + threadIdx.x;
  int i = gid >> 5, lane = gid & 31;
  if (i >= n) return;
  int beg = indptr[i], end = indptr[i + 1];
  float di = dinv[i];
  float acc = 0.f;
  int e = beg;
  for (; e + 3 < end; e += 4) {
    float2 p0 = sedge[e], p1 = sedge[e + 1], p2 = sedge[e + 2], p3 = sedge[e + 3];
    float v0 = x[(size_t)__float_as_int(p0.x) * 32 + lane];
    float v1 = x[(size_t)__float_as_int(p1.x) * 32 + lane];
    float v2 = x[(size_t)__float_as_int(p2.x) * 32 + lane];
    float v3 = x[(size_t)__float_as_int(p3.x) * 32 + lane];
    acc = fmaf(v0, p0.y, acc);
    acc = fmaf(v1, p1.y, acc);
    acc = fmaf(v2, p2.y, acc);
    acc = fmaf(v3, p3.y, acc);
  }
  for (; e < end; ++e) {
    float2 p = sedge[e];
    acc = fmaf(x[(size_t)__float_as_int(p.x) * 32 + lane], p.y, acc);
  }
  acc = fmaf(x[(size_t)i * 32 + lane], di, acc);  // self-loop: weight dinv[i]
  out[(size_t)i * 32 + lane] = acc * di;          // hoisted dinv[col]
}

// One wave per node. sedge.y = dinv[row]*ew.
// out[i,:] = dinv[i]*( sum_e w_e*xw[row_e,:] + dinv[i]*xw[i,:] ) + bias
template <int F>
__global__ void agg_kernel(const float* __restrict__ xw, const int* __restrict__ indptr,
                           const float2* __restrict__ sedge, const float* __restrict__ dinv,
                           const float* __restrict__ bias, float* __restrict__ out, int n) {
  int gid = blockIdx.x * blockDim.x + threadIdx.x;
  int i = gid >> 6, lane = gid & 63;
  if (i >= n) return;
  int beg = indptr[i], end = indptr[i + 1];
  float di = dinv[i];
  if (F == 128) {
    const float2* x2 = (const float2*)xw;
    float2 acc = make_float2(0.f, 0.f);
    int e = beg;
    for (; e + 3 < end; e += 4) {  // 4-deep ILP on the gather chain
      float2 p0 = sedge[e], p1 = sedge[e + 1], p2 = sedge[e + 2], p3 = sedge[e + 3];
      float2 v0 = x2[(size_t)__float_as_int(p0.x) * 64 + lane];
      float2 v1 = x2[(size_t)__float_as_int(p1.x) * 64 + lane];
      float2 v2 = x2[(size_t)__float_as_int(p2.x) * 64 + lane];
      float2 v3 = x2[(size_t)__float_as_int(p3.x) * 64 + lane];
      acc.x = fmaf(v0.x, p0.y, acc.x); acc.y = fmaf(v0.y, p0.y, acc.y);
      acc.x = fmaf(v1.x, p1.y, acc.x); acc.y = fmaf(v1.y, p1.y, acc.y);
      acc.x = fmaf(v2.x, p2.y, acc.x); acc.y = fmaf(v2.y, p2.y, acc.y);
      acc.x = fmaf(v3.x, p3.y, acc.x); acc.y = fmaf(v3.y, p3.y, acc.y);
    }
    for (; e < end; ++e) {
      float2 p = sedge[e];
      float2 v = x2[(size_t)__float_as_int(p.x) * 64 + lane];
      acc.x = fmaf(v.x, p.y, acc.x);
      acc.y = fmaf(v.y, p.y, acc.y);
    }
    float2 vs = x2[(size_t)i * 64 + lane];
    float2 b = ((const float2*)bias)[lane];
    acc.x = fmaf(vs.x, di, acc.x);
    acc.y = fmaf(vs.y, di, acc.y);
    acc.x = fmaf(acc.x, di, b.x);
    acc.y = fmaf(acc.y, di, b.y);
    ((float2*)out)[(size_t)i * 64 + lane] = acc;
  } else {
    float acc = 0.f;
    int e = beg;
    for (; e + 3 < end; e += 4) {
      float2 p0 = sedge[e], p1 = sedge[e + 1], p2 = sedge[e + 2], p3 = sedge[e + 3];
      float v0 = xw[(size_t)__float_as_int(p0.x) * 64 + lane];
      float v1 = xw[(size_t)__float_as_int(p1.x) * 64 + lane];
      float v2 = xw[(size_t)__float_as_int(p2.x) * 64 + lane];
      float v3 = xw[(size_t)__float_as_int(p3.x) * 64 + lane];
      acc = fmaf(v0, p0.y, acc);
      acc = fmaf(v1, p1.y, acc);
      acc = fmaf(v2, p2.y, acc);
      acc = fmaf(v3, p3.y, acc);
    }
    for (; e < end; ++e) {
      float2 p = sedge[e];
      acc = fmaf(xw[(size_t)__float_as_int(p.x) * 64 + lane], p.y, acc);
    }
    acc = fmaf(xw[(size_t)i * 64 + lane], di, acc);
    out[(size_t)i * 64 + lane] = fmaf(acc, di, bias[lane]);
  }
}

// BN stage 1: per-block column partial sums (f64), no atomics.
// 256 threads: col group cg = t&31 (4 cols), row lane rl = t>>5 (8 rows/iter).
__global__ __launch_bounds__(256) void bn_part_kernel(const float* __restrict__ h,
                                                      double* __restrict__ partial, int n) {
  __shared__ double sred[256][8];  // [thread][4 cols x {sum,sumsq}] = 16 KB
  int t = threadIdx.x;
  int cg = t & 31, rl = t >> 5;
  int rpb = (n + gridDim.x - 1) / gridDim.x;
  int r0 = blockIdx.x * rpb;
  int r1 = min(r0 + rpb, n);
  double s0 = 0, s1 = 0, s2 = 0, s3 = 0, q0 = 0, q1 = 0, q2 = 0, q3 = 0;
  for (int r = r0 + rl; r < r1; r += 8) {
    float4 v = *(const float4*)&h[(size_t)r * 128 + cg * 4];
    s0 += v.x; q0 += (double)v.x * v.x;
    s1 += v.y; q1 += (double)v.y * v.y;
    s2 += v.z; q2 += (double)v.z * v.z;
    s3 += v.w; q3 += (double)v.w * v.w;
  }
  sred[t][0] = s0; sred[t][1] = s1; sred[t][2] = s2; sred[t][3] = s3;
  sred[t][4] = q0; sred[t][5] = q1; sred[t][6] = q2; sred[t][7] = q3;
  __syncthreads();
  if (rl == 0) {
#pragma unroll
    for (int o = 1; o < 8; ++o) {
      double* p = sred[o * 32 + cg];
      s0 += p[0]; s1 += p[1]; s2 += p[2]; s3 += p[3];
      q0 += p[4]; q1 += p[5]; q2 += p[6]; q3 += p[7];
    }
    double* dst = partial + (size_t)blockIdx.x * 256 + cg * 8;
    dst[0] = s0; dst[1] = q0;
    dst[2] = s1; dst[3] = q1;
    dst[4] = s2; dst[5] = q2;
    dst[6] = s3; dst[7] = q3;
  }
}

// BN stage 2: reduce partials + finalize scale/shift. 128 threads (one/column).
__global__ void bn_reduce_finalize_kernel(const double* __restrict__ partial,
                                          const float* __restrict__ gamma,
                                          const float* __restrict__ beta,
                                          float2* __restrict__ ss, int n, int nb) {
  int c = threadIdx.x;  // 128
  double s = 0.0, q = 0.0;
  for (int b = 0; b < nb; ++b) {
    const double* p = partial + (size_t)b * 256 + c * 2;
    s += p[0];
    q += p[1];
  }
  double mean = s / n;
  double var = q / n - mean * mean;
  float inv = (float)(1.0 / sqrt(var + 1e-5));
  float scale = gamma[c] * inv;
  float shift = beta[c] - (float)mean * scale;
  ss[c] = make_float2(scale, shift);
}

// Fused decoder: 64 label-edges/block. z1 = relu(P[src,0:64]+P[dst,64:128]+db1)
// -> relu(z1@dw2+db2) -> dot dw3 + db3, shuffle-reduced.
__global__ __launch_bounds__(256) void decoder_kernel(
    const float* __restrict__ P, const int* __restrict__ eli, int L,
    const float* __restrict__ db1,
    const float* __restrict__ dw2, const float* __restrict__ db2,
    const float* __restrict__ dw3, const float* __restrict__ db3,
    float* __restrict__ out) {
  __shared__ float z1t[64 * 64];  // z1t[c][swz(c,r)]
  __shared__ float w2l[64 * 64];  // w2l[k][c]
  int t = threadIdx.x;
  int l0 = blockIdx.x * 64;
  for (int e = t; e < 4096; e += 256) w2l[e] = dw2[e];
  // gather P rows (float4), add halves + bias, relu -> transposed swizzled LDS
  for (int e = t; e < 1024; e += 256) {  // 1024 float4 elements = 64 edges x 16
    int r = e >> 4, c4 = e & 15;
    int l = l0 + r;
    float4 v = make_float4(0.f, 0.f, 0.f, 0.f);
    if (l < L) {
      int src = eli[l], dst = eli[L + l];
      float4 a = *(const float4*)&P[(size_t)src * 128 + c4 * 4];
      float4 b = *(const float4*)&P[(size_t)dst * 128 + 64 + c4 * 4];
      float4 d = *(const float4*)&db1[c4 * 4];
      v.x = frelu(a.x + b.x + d.x);
      v.y = frelu(a.y + b.y + d.y);
      v.z = frelu(a.z + b.z + d.z);
      v.w = frelu(a.w + b.w + d.w);
    }
    int c = c4 * 4;
    z1t[(c + 0) * 64 + swz(c + 0, r)] = v.x;
    z1t[(c + 1) * 64 + swz(c + 1, r)] = v.y;
    z1t[(c + 2) * 64 + swz(c + 2, r)] = v.z;
    z1t[(c + 3) * 64 + swz(c + 3, r)] = v.w;
  }
  __syncthreads();

  int tx = t & 15, ty = t >> 4;  // cols tx*4.., rows(edges) ty*4..
  float acc2[4][4] = {};
#pragma unroll 8
  for (int k = 0; k < 64; ++k) {
    float4 a4 = *(const float4*)&z1t[k * 64 + swz(k, ty * 4)];
    float4 b4 = *(const float4*)&w2l[k * 64 + tx * 4];
    float a[4] = {a4.x, a4.y, a4.z, a4.w};
    float b[4] = {b4.x, b4.y, b4.z, b4.w};
#pragma unroll
    for (int i = 0; i < 4; ++i)
#pragma unroll
      for (int j = 0; j < 4; ++j) acc2[i][j] = fmaf(a[i], b[j], acc2[i][j]);
  }
  float4 db2v = *(const float4*)&db2[tx * 4];
  float4 dw3v = *(const float4*)&dw3[tx * 4];
  float db2a[4] = {db2v.x, db2v.y, db2v.z, db2v.w};
  float dw3a[4] = {dw3v.x, dw3v.y, dw3v.z, dw3v.w};
  float p[4];
#pragma unroll
  for (int i = 0; i < 4; ++i) {
    float s = 0.f;
#pragma unroll
    for (int j = 0; j < 4; ++j) s = fmaf(frelu(acc2[i][j] + db2a[j]), dw3a[j], s);
    // reduce across the 16 tx lanes of this ty group
#pragma unroll
    for (int m = 1; m < 16; m <<= 1) s += __shfl_xor(s, m);
    p[i] = s;
  }
  if (tx == 0) {
    int l = l0 + ty * 4;
    if (l + 3 < L) {
      float b3 = db3[0];
      float4 o = make_float4(p[0] + b3, p[1] + b3, p[2] + b3, p[3] + b3);
      *(float4*)&out[l] = o;
    } else {
      for (int i = 0; i < 4; ++i)
        if (l + i < L) out[l + i] = p[i] + db3[0];
    }
  }
}

extern "C" void kernel_launch(void* const* d_in, const int* in_sizes, int n_in,
                              void* d_out, int out_size, void* d_ws, size_t ws_size,
                              hipStream_t stream) {
  const float* x = (const float*)d_in[0];
  const int* edge_index = (const int*)d_in[1];
  const float* ew = (const float*)d_in[2];
  const int* eli = (const int*)d_in[3];
  const float* w1 = (const float*)d_in[4];
  const float* b1 = (const float*)d_in[5];
  const float* w2 = (const float*)d_in[6];
  const float* b2 = (const float*)d_in[7];
  const float* w3 = (const float*)d_in[8];
  const float* b3 = (const float*)d_in[9];
  const float* w4 = (const float*)d_in[10];
  const float* b4 = (const float*)d_in[11];
  const float* bn_gamma = (const float*)d_in[12];
  const float* bn_beta = (const float*)d_in[13];
  const float* dw1 = (const float*)d_in[14];
  const float* db1 = (const float*)d_in[15];
  const float* dw2 = (const float*)d_in[16];
  const float* db2 = (const float*)d_in[17];
  const float* dw3 = (const float*)d_in[18];
  const float* db3 = (const float*)d_in[19];

  const int n = in_sizes[0] / 32;
  const int E = in_sizes[2];
  const int L = out_size;
  const int* rowv = edge_index;      // edge_index[0]
  const int* colv = edge_index + E;  // edge_index[1]

  char* ws = (char*)d_ws;
  size_t off = 0;
  float* bufA = (float*)(ws + off); off += (size_t)n * 128 * 4;
  float* bufB = (float*)(ws + off); off += (size_t)n * 128 * 4;
  float* dinv = (float*)(ws + off); off += (size_t)n * 4;
  int* hist = (int*)(ws + off);     off += (size_t)n * 4;
  int* indptr = (int*)(ws + off);   off += (size_t)(n + 1) * 4;
  off = (off + 255) & ~(size_t)255;
  int* rank = (int*)(ws + off);     off += (size_t)E * 4;
  off = (off + 255) & ~(size_t)255;
  float2* sedge = (float2*)(ws + off); off += (size_t)E * 8;
  off = (off + 255) & ~(size_t)255;
  double* bnpart = (double*)(ws + off); off += (size_t)BN_BLOCKS * 256 * 8;
  float2* bnss = (float2*)(ws + off);   off += 128 * 8;

  int eblocks = (E + 255) / 256;
  int nblocks = (n + 255) / 256;

  // ---- CSR build (single atomic pass) ----
  hipMemsetAsync(hist, 0, (size_t)n * 4, stream);
  hist_rank_kernel<<<eblocks, 256, 0, stream>>>(colv, hist, rank, E);
  scan_kernel<<<1, 1024, 0, stream>>>(hist, indptr, n);
  scatter_kernel<<<eblocks, 256, 0, stream>>>(rowv, colv, ew, indptr, rank, sedge, E);
  deg_dinv_kernel<<<nblocks, 256, 0, stream>>>(sedge, indptr, dinv, n);
  edgew_kernel<<<eblocks, 256, 0, stream>>>(sedge, dinv, E);

  dim3 gemm_grid128((n + 63) / 64, 2);
  dim3 gemm_grid64((n + 63) / 64, 1);
  int agg_blocks = (n * 64 + 255) / 256;
  int agg32_blocks = (n * 32 + 255) / 256;

  // ---- layer 1: agg x (32-dim) FIRST, then GEMM 32->128 (+b1); BN stats ----
  agg32_kernel<<<agg32_blocks, 256, 0, stream>>>(x, indptr, sedge, dinv, bufA, n);
  gemm_kernel<32><<<gemm_grid128, 256, 0, stream>>>(bufA, w1, bufB, n, 128, nullptr, b1);
  bn_part_kernel<<<BN_BLOCKS, 256, 0, stream>>>(bufB, bnpart, n);
  bn_reduce_finalize_kernel<<<1, 128, 0, stream>>>(bnpart, bn_gamma, bn_beta, bnss, n, BN_BLOCKS);

  // ---- layer 2 (BN1+ReLU fused into A-staging) ----
  gemm_kernel<128><<<gemm_grid128, 256, 0, stream>>>(bufB, w2, bufA, n, 128, bnss, nullptr);
  agg_kernel<128><<<agg_blocks, 256, 0, stream>>>(bufA, indptr, sedge, dinv, b2, bufB, n);
  bn_part_kernel<<<BN_BLOCKS, 256, 0, stream>>>(bufB, bnpart, n);
  bn_reduce_finalize_kernel<<<1, 128, 0, stream>>>(bnpart, bn_gamma + 128, bn_beta + 128, bnss, n,
                                                   BN_BLOCKS);

  // ---- layer 3 ----
  gemm_kernel<128><<<gemm_grid128, 256, 0, stream>>>(bufB, w3, bufA, n, 128, bnss, nullptr);
  agg_kernel<128><<<agg_blocks, 256, 0, stream>>>(bufA, indptr, sedge, dinv, b3, bufB, n);
  bn_part_kernel<<<BN_BLOCKS, 256, 0, stream>>>(bufB, bnpart, n);
  bn_reduce_finalize_kernel<<<1, 128, 0, stream>>>(bnpart, bn_gamma + 256, bn_beta + 256, bnss, n,
                                                   BN_BLOCKS);

  // ---- layer 4: enc = conv(relu(bn3(h3)), w4, b4)  [n,64] ----
  gemm_kernel<128><<<gemm_grid64, 256, 0, stream>>>(bufB, w4, bufA, n, 64, bnss, nullptr);
  agg_kernel<64><<<agg_blocks, 256, 0, stream>>>(bufA, indptr, sedge, dinv, b4, bufB, n);

  // ---- decoder: P = [enc@dw1_top | enc@dw1_bot] -> fused per-edge MLP ----
  pre_gemm_kernel<<<dim3((n + 63) / 64, 2), 256, 0, stream>>>(bufB, dw1, bufA, n);
  decoder_kernel<<<(L + 63) / 64, 256, 0, stream>>>(bufA, eli, L, db1, dw2, db2, dw3, db3,
                                                    (float*)d_out);
}

// Round 13
// 637.765 us; speedup vs baseline: 1.5614x; 1.5614x over previous
//
#include <hip/hip_runtime.h>

// ---------------------------------------------------------------------------
// GCN link predictor: 3x (GCNConv -> BN -> ReLU) -> GCNConv -> edge MLP decoder
//   - CSR build, atomic-minimized (R8): hist atomic RETURNS rank -> scatter is
//     atomic-free; deg derived from CSR segments; dinv folded into edge weight.
//   - BN stats (R9/R10): two-stage atomic-free reduction. Stage 1: 512 blocks,
//     float4 loads, f64 partials via LDS tree. Stage 2 (R10 fix): ONE BLOCK
//     PER COLUMN (128 x 256), shuffle+LDS reduce — the R9 single-block version
//     was a 512-deep serial f64 load chain on one CU (125 us, 0.02% occ).
//   - Layer 1: aggregate raw x (32-dim) FIRST, then GEMM (conv commutes).
//     Layers 2-4: GEMM (fused BN+ReLU of prev layer in A-staging) ->
//     wave-per-node aggregation (no atomics, 4-deep ILP)
//   - GEMM: 64x64 tile, K chunked in BK=64 stages -> 32KB LDS
//   - Decoder: first MLP layer hoisted to node level; per-edge kernel =
//     gather+bias+relu -> 64x64 MLP2 -> dot, shuffle-reduced.
// LDS swizzle: c' = c ^ (((k>>2)&7)<<2) (see R4 notes).
// ---------------------------------------------------------------------------

#define BN_BLOCKS 512

__device__ __forceinline__ float frelu(float v) { return v > 0.f ? v : 0.f; }
__device__ __forceinline__ int swz(int k, int c) { return c ^ (((k >> 2) & 7) << 2); }

// rank[e] = arrival index of edge e within its destination bin (also builds hist)
__global__ void hist_rank_kernel(const int* __restrict__ col, int* __restrict__ hist,
                                 int* __restrict__ rank, int E) {
  int e = blockIdx.x * blockDim.x + threadIdx.x;
  if (e < E) rank[e] = atomicAdd(&hist[col[e]], 1);
}

// Single-block exclusive scan over hist[n] -> indptr[n+1]. 1024 threads.
__global__ void scan_kernel(const int* __restrict__ hist, int* __restrict__ indptr, int n) {
  __shared__ int wsum[16];
  __shared__ int carry_s;
  int t = threadIdx.x, lane = t & 63, w = t >> 6;
  if (t == 0) carry_s = 0;
  __syncthreads();
  for (int base = 0; base < n; base += 1024) {
    int i = base + t;
    int v = (i < n) ? hist[i] : 0;
    int incl = v;
#pragma unroll
    for (int off = 1; off < 64; off <<= 1) {
      int u = __shfl_up(incl, off);
      if (lane >= off) incl += u;
    }
    if (lane == 63) wsum[w] = incl;
    __syncthreads();
    int woff = 0;
    for (int q = 0; q < w; ++q) woff += wsum[q];
    int excl = carry_s + woff + (incl - v);
    if (i < n) indptr[i] = excl;
    __syncthreads();
    if (t == 1023) carry_s += woff + incl;  // chunk total
    __syncthreads();
  }
  if (threadIdx.x == 0) indptr[n] = carry_s;
}

// Atomic-free scatter: sedge[indptr[col]+rank] = { bitcast(row), ew }
__global__ void scatter_kernel(const int* __restrict__ row, const int* __restrict__ col,
                               const float* __restrict__ ew, const int* __restrict__ indptr,
                               const int* __restrict__ rank, float2* __restrict__ sedge, int E) {
  int e = blockIdx.x * blockDim.x + threadIdx.x;
  if (e < E) {
    int pos = indptr[col[e]] + rank[e];
    sedge[pos] = make_float2(__int_as_float(row[e]), ew[e]);
  }
}

// deg from CSR segments (no atomics): deg[i] = 1 (self) + sum ew; dinv = rsqrt
__global__ void deg_dinv_kernel(const float2* __restrict__ sedge, const int* __restrict__ indptr,
                                float* __restrict__ dinv, int n) {
  int i = blockIdx.x * blockDim.x + threadIdx.x;
  if (i >= n) return;
  int beg = indptr[i], end = indptr[i + 1];
  float s = 1.0f;  // self-loop weight
  for (int e = beg; e < end; ++e) s += sedge[e].y;
  dinv[i] = rsqrtf(s);
}

// Fold dinv[row] into the stored weight: sedge[p].y *= dinv[row_p]
__global__ void edgew_kernel(float2* __restrict__ sedge, const float* __restrict__ dinv, int E) {
  int p = blockIdx.x * blockDim.x + threadIdx.x;
  if (p < E) {
    float2 v = sedge[p];
    v.y *= dinv[__float_as_int(v.x)];
    sedge[p] = v;
  }
}

// C[n,F] = act(A)[n,K] @ W[K,F] (+bias).  64x64 tile, 256 threads, 4x4/thread.
// K chunked in BK<=64 stages -> 32KB LDS max. If ss != nullptr, A-staging
// applies relu(a*ss[k].x + ss[k].y) (fused BN+ReLU of the previous layer).
template <int K>
__global__ __launch_bounds__(256) void gemm_kernel(const float* __restrict__ A,
                                                   const float* __restrict__ W,
                                                   float* __restrict__ C, int n, int F,
                                                   const float2* __restrict__ ss,
                                                   const float* __restrict__ bias) {
  constexpr int BK = (K > 64) ? 64 : K;
  __shared__ float At[BK * 64];  // At[kk][swz(kk,r)]
  __shared__ float Wl[BK * 64];  // Wl[kk][c]
  int t = threadIdx.x;
  int r0 = blockIdx.x * 64, c0 = blockIdx.y * 64;
  int tx = t & 15, ty = t >> 4;
  float acc[4][4] = {};
  for (int k0 = 0; k0 < K; k0 += BK) {
    if (k0) __syncthreads();  // previous chunk's compute done before overwrite
    for (int e = t; e < 64 * BK; e += 256) {
      int r = e / BK, kk = e % BK;  // kk lane-fast: coalesced global read
      int k = k0 + kk;
      float v = (r0 + r < n) ? A[(size_t)(r0 + r) * K + k] : 0.f;
      if (ss) {
        float2 s = ss[k];
        v = frelu(fmaf(v, s.x, s.y));
      }
      At[kk * 64 + swz(kk, r)] = v;
    }
    for (int e = t; e < BK * 64; e += 256) {
      int kk = e >> 6, c = e & 63;
      Wl[e] = W[(size_t)(k0 + kk) * F + c0 + c];
    }
    __syncthreads();
#pragma unroll 8
    for (int kk = 0; kk < BK; ++kk) {
      float4 a4 = *(const float4*)&At[kk * 64 + swz(kk, ty * 4)];
      float4 b4 = *(const float4*)&Wl[kk * 64 + tx * 4];
      float a[4] = {a4.x, a4.y, a4.z, a4.w};
      float b[4] = {b4.x, b4.y, b4.z, b4.w};
#pragma unroll
      for (int i = 0; i < 4; ++i)
#pragma unroll
        for (int j = 0; j < 4; ++j) acc[i][j] = fmaf(a[i], b[j], acc[i][j]);
    }
  }
  float4 bv = make_float4(0.f, 0.f, 0.f, 0.f);
  if (bias) bv = *(const float4*)&bias[c0 + tx * 4];
#pragma unroll
  for (int i = 0; i < 4; ++i) {
    int r = r0 + ty * 4 + i;
    if (r < n) {
      float4 o = make_float4(acc[i][0] + bv.x, acc[i][1] + bv.y, acc[i][2] + bv.z,
                             acc[i][3] + bv.w);
      *(float4*)&C[(size_t)r * F + c0 + tx * 4] = o;
    }
  }
}

// P[n,128]: cols 0..63 = enc @ dw1[0:64,:], cols 64..127 = enc @ dw1[64:128,:]
__global__ __launch_bounds__(256) void pre_gemm_kernel(const float* __restrict__ enc,
                                                       const float* __restrict__ dw1,
                                                       float* __restrict__ P, int n) {
  __shared__ float At[64 * 64];
  __shared__ float Wl[64 * 64];
  int t = threadIdx.x;
  int r0 = blockIdx.x * 64;
  const float* W = dw1 + blockIdx.y * 4096;  // [64,64] half of dw1
  for (int e = t; e < 64 * 64; e += 256) {
    int r = e >> 6, k = e & 63;
    At[k * 64 + swz(k, r)] = (r0 + r < n) ? enc[(size_t)(r0 + r) * 64 + k] : 0.f;
  }
  for (int e = t; e < 4096; e += 256) Wl[e] = W[e];
  __syncthreads();
  int tx = t & 15, ty = t >> 4;
  float acc[4][4] = {};
#pragma unroll 8
  for (int k = 0; k < 64; ++k) {
    float4 a4 = *(const float4*)&At[k * 64 + swz(k, ty * 4)];
    float4 b4 = *(const float4*)&Wl[k * 64 + tx * 4];
    float a[4] = {a4.x, a4.y, a4.z, a4.w};
    float b[4] = {b4.x, b4.y, b4.z, b4.w};
#pragma unroll
    for (int i = 0; i < 4; ++i)
#pragma unroll
      for (int j = 0; j < 4; ++j) acc[i][j] = fmaf(a[i], b[j], acc[i][j]);
  }
#pragma unroll
  for (int i = 0; i < 4; ++i) {
    int r = r0 + ty * 4 + i;
    if (r < n) {
      float4 o = make_float4(acc[i][0], acc[i][1], acc[i][2], acc[i][3]);
      *(float4*)&P[(size_t)r * 128 + blockIdx.y * 64 + tx * 4] = o;
    }
  }
}

// Layer-1 aggregation on raw x [n,32]: 2 nodes per wave, 32 lanes each.
// sedge.y = dinv[row]*ew.  out[i,k] = dinv[i]*( sum_e w_e*x[row_e,k] + dinv[i]*x[i,k] )
__global__ void agg32_kernel(const float* __restrict__ x, const int* __restrict__ indptr,
                             const float2* __restrict__ sedge, const float* __restrict__ dinv,
                             float* __restrict__ out, int n) {
  int gid = blockIdx.x * blockDim.x + threadIdx.x;
  int i = gid >> 5, lane = gid & 31;
  if (i >= n) return;
  int beg = indptr[i], end = indptr[i + 1];
  float di = dinv[i];
  float acc = 0.f;
  int e = beg;
  for (; e + 3 < end; e += 4) {
    float2 p0 = sedge[e], p1 = sedge[e + 1], p2 = sedge[e + 2], p3 = sedge[e + 3];
    float v0 = x[(size_t)__float_as_int(p0.x) * 32 + lane];
    float v1 = x[(size_t)__float_as_int(p1.x) * 32 + lane];
    float v2 = x[(size_t)__float_as_int(p2.x) * 32 + lane];
    float v3 = x[(size_t)__float_as_int(p3.x) * 32 + lane];
    acc = fmaf(v0, p0.y, acc);
    acc = fmaf(v1, p1.y, acc);
    acc = fmaf(v2, p2.y, acc);
    acc = fmaf(v3, p3.y, acc);
  }
  for (; e < end; ++e) {
    float2 p = sedge[e];
    acc = fmaf(x[(size_t)__float_as_int(p.x) * 32 + lane], p.y, acc);
  }
  acc = fmaf(x[(size_t)i * 32 + lane], di, acc);  // self-loop: weight dinv[i]
  out[(size_t)i * 32 + lane] = acc * di;          // hoisted dinv[col]
}

// One wave per node. sedge.y = dinv[row]*ew.
// out[i,:] = dinv[i]*( sum_e w_e*xw[row_e,:] + dinv[i]*xw[i,:] ) + bias
template <int F>
__global__ void agg_kernel(const float* __restrict__ xw, const int* __restrict__ indptr,
                           const float2* __restrict__ sedge, const float* __restrict__ dinv,
                           const float* __restrict__ bias, float* __restrict__ out, int n) {
  int gid = blockIdx.x * blockDim.x + threadIdx.x;
  int i = gid >> 6, lane = gid & 63;
  if (i >= n) return;
  int beg = indptr[i], end = indptr[i + 1];
  float di = dinv[i];
  if (F == 128) {
    const float2* x2 = (const float2*)xw;
    float2 acc = make_float2(0.f, 0.f);
    int e = beg;
    for (; e + 3 < end; e += 4) {  // 4-deep ILP on the gather chain
      float2 p0 = sedge[e], p1 = sedge[e + 1], p2 = sedge[e + 2], p3 = sedge[e + 3];
      float2 v0 = x2[(size_t)__float_as_int(p0.x) * 64 + lane];
      float2 v1 = x2[(size_t)__float_as_int(p1.x) * 64 + lane];
      float2 v2 = x2[(size_t)__float_as_int(p2.x) * 64 + lane];
      float2 v3 = x2[(size_t)__float_as_int(p3.x) * 64 + lane];
      acc.x = fmaf(v0.x, p0.y, acc.x); acc.y = fmaf(v0.y, p0.y, acc.y);
      acc.x = fmaf(v1.x, p1.y, acc.x); acc.y = fmaf(v1.y, p1.y, acc.y);
      acc.x = fmaf(v2.x, p2.y, acc.x); acc.y = fmaf(v2.y, p2.y, acc.y);
      acc.x = fmaf(v3.x, p3.y, acc.x); acc.y = fmaf(v3.y, p3.y, acc.y);
    }
    for (; e < end; ++e) {
      float2 p = sedge[e];
      float2 v = x2[(size_t)__float_as_int(p.x) * 64 + lane];
      acc.x = fmaf(v.x, p.y, acc.x);
      acc.y = fmaf(v.y, p.y, acc.y);
    }
    float2 vs = x2[(size_t)i * 64 + lane];
    float2 b = ((const float2*)bias)[lane];
    acc.x = fmaf(vs.x, di, acc.x);
    acc.y = fmaf(vs.y, di, acc.y);
    acc.x = fmaf(acc.x, di, b.x);
    acc.y = fmaf(acc.y, di, b.y);
    ((float2*)out)[(size_t)i * 64 + lane] = acc;
  } else {
    float acc = 0.f;
    int e = beg;
    for (; e + 3 < end; e += 4) {
      float2 p0 = sedge[e], p1 = sedge[e + 1], p2 = sedge[e + 2], p3 = sedge[e + 3];
      float v0 = xw[(size_t)__float_as_int(p0.x) * 64 + lane];
      float v1 = xw[(size_t)__float_as_int(p1.x) * 64 + lane];
      float v2 = xw[(size_t)__float_as_int(p2.x) * 64 + lane];
      float v3 = xw[(size_t)__float_as_int(p3.x) * 64 + lane];
      acc = fmaf(v0, p0.y, acc);
      acc = fmaf(v1, p1.y, acc);
      acc = fmaf(v2, p2.y, acc);
      acc = fmaf(v3, p3.y, acc);
    }
    for (; e < end; ++e) {
      float2 p = sedge[e];
      acc = fmaf(xw[(size_t)__float_as_int(p.x) * 64 + lane], p.y, acc);
    }
    acc = fmaf(xw[(size_t)i * 64 + lane], di, acc);
    out[(size_t)i * 64 + lane] = fmaf(acc, di, bias[lane]);
  }
}

// BN stage 1: per-block column partial sums (f64), no atomics.
// 256 threads: col group cg = t&31 (4 cols), row lane rl = t>>5 (8 rows/iter).
__global__ __launch_bounds__(256) void bn_part_kernel(const float* __restrict__ h,
                                                      double* __restrict__ partial, int n) {
  __shared__ double sred[256][8];  // [thread][4 cols x {sum,sumsq}] = 16 KB
  int t = threadIdx.x;
  int cg = t & 31, rl = t >> 5;
  int rpb = (n + gridDim.x - 1) / gridDim.x;
  int r0 = blockIdx.x * rpb;
  int r1 = min(r0 + rpb, n);
  double s0 = 0, s1 = 0, s2 = 0, s3 = 0, q0 = 0, q1 = 0, q2 = 0, q3 = 0;
  for (int r = r0 + rl; r < r1; r += 8) {
    float4 v = *(const float4*)&h[(size_t)r * 128 + cg * 4];
    s0 += v.x; q0 += (double)v.x * v.x;
    s1 += v.y; q1 += (double)v.y * v.y;
    s2 += v.z; q2 += (double)v.z * v.z;
    s3 += v.w; q3 += (double)v.w * v.w;
  }
  sred[t][0] = s0; sred[t][1] = s1; sred[t][2] = s2; sred[t][3] = s3;
  sred[t][4] = q0; sred[t][5] = q1; sred[t][6] = q2; sred[t][7] = q3;
  __syncthreads();
  if (rl == 0) {
#pragma unroll
    for (int o = 1; o < 8; ++o) {
      double* p = sred[o * 32 + cg];
      s0 += p[0]; s1 += p[1]; s2 += p[2]; s3 += p[3];
      q0 += p[4]; q1 += p[5]; q2 += p[6]; q3 += p[7];
    }
    double* dst = partial + (size_t)blockIdx.x * 256 + cg * 8;
    dst[0] = s0; dst[1] = q0;
    dst[2] = s1; dst[3] = q1;
    dst[4] = s2; dst[5] = q2;
    dst[6] = s3; dst[7] = q3;
  }
}

// BN stage 2 (R10): ONE BLOCK PER COLUMN, 256 threads. Each thread sums
// nb/256 partials; 64-lane shuffle + LDS combine; thread 0 finalizes.
__global__ __launch_bounds__(256) void bn_reduce_finalize_kernel(
    const double* __restrict__ partial, const float* __restrict__ gamma,
    const float* __restrict__ beta, float2* __restrict__ ss, int n, int nb) {
  __shared__ double sred[4][2];
  int c = blockIdx.x;  // 0..127
  int t = threadIdx.x;
  double s = 0.0, q = 0.0;
  for (int b = t; b < nb; b += 256) {
    const double* p = partial + (size_t)b * 256 + c * 2;
    s += p[0];
    q += p[1];
  }
#pragma unroll
  for (int m = 1; m < 64; m <<= 1) {
    s += __shfl_xor(s, m, 64);
    q += __shfl_xor(q, m, 64);
  }
  int w = t >> 6, lane = t & 63;
  if (lane == 0) {
    sred[w][0] = s;
    sred[w][1] = q;
  }
  __syncthreads();
  if (t == 0) {
    s = sred[0][0] + sred[1][0] + sred[2][0] + sred[3][0];
    q = sred[0][1] + sred[1][1] + sred[2][1] + sred[3][1];
    double mean = s / n;
    double var = q / n - mean * mean;
    float inv = (float)(1.0 / sqrt(var + 1e-5));
    float scale = gamma[c] * inv;
    float shift = beta[c] - (float)mean * scale;
    ss[c] = make_float2(scale, shift);
  }
}

// Fused decoder: 64 label-edges/block. z1 = relu(P[src,0:64]+P[dst,64:128]+db1)
// -> relu(z1@dw2+db2) -> dot dw3 + db3, shuffle-reduced.
__global__ __launch_bounds__(256) void decoder_kernel(
    const float* __restrict__ P, const int* __restrict__ eli, int L,
    const float* __restrict__ db1,
    const float* __restrict__ dw2, const float* __restrict__ db2,
    const float* __restrict__ dw3, const float* __restrict__ db3,
    float* __restrict__ out) {
  __shared__ float z1t[64 * 64];  // z1t[c][swz(c,r)]
  __shared__ float w2l[64 * 64];  // w2l[k][c]
  int t = threadIdx.x;
  int l0 = blockIdx.x * 64;
  for (int e = t; e < 4096; e += 256) w2l[e] = dw2[e];
  // gather P rows (float4), add halves + bias, relu -> transposed swizzled LDS
  for (int e = t; e < 1024; e += 256) {  // 1024 float4 elements = 64 edges x 16
    int r = e >> 4, c4 = e & 15;
    int l = l0 + r;
    float4 v = make_float4(0.f, 0.f, 0.f, 0.f);
    if (l < L) {
      int src = eli[l], dst = eli[L + l];
      float4 a = *(const float4*)&P[(size_t)src * 128 + c4 * 4];
      float4 b = *(const float4*)&P[(size_t)dst * 128 + 64 + c4 * 4];
      float4 d = *(const float4*)&db1[c4 * 4];
      v.x = frelu(a.x + b.x + d.x);
      v.y = frelu(a.y + b.y + d.y);
      v.z = frelu(a.z + b.z + d.z);
      v.w = frelu(a.w + b.w + d.w);
    }
    int c = c4 * 4;
    z1t[(c + 0) * 64 + swz(c + 0, r)] = v.x;
    z1t[(c + 1) * 64 + swz(c + 1, r)] = v.y;
    z1t[(c + 2) * 64 + swz(c + 2, r)] = v.z;
    z1t[(c + 3) * 64 + swz(c + 3, r)] = v.w;
  }
  __syncthreads();

  int tx = t & 15, ty = t >> 4;  // cols tx*4.., rows(edges) ty*4..
  float acc2[4][4] = {};
#pragma unroll 8
  for (int k = 0; k < 64; ++k) {
    float4 a4 = *(const float4*)&z1t[k * 64 + swz(k, ty * 4)];
    float4 b4 = *(const float4*)&w2l[k * 64 + tx * 4];
    float a[4] = {a4.x, a4.y, a4.z, a4.w};
    float b[4] = {b4.x, b4.y, b4.z, b4.w};
#pragma unroll
    for (int i = 0; i < 4; ++i)
#pragma unroll
      for (int j = 0; j < 4; ++j) acc2[i][j] = fmaf(a[i], b[j], acc2[i][j]);
  }
  float4 db2v = *(const float4*)&db2[tx * 4];
  float4 dw3v = *(const float4*)&dw3[tx * 4];
  float db2a[4] = {db2v.x, db2v.y, db2v.z, db2v.w};
  float dw3a[4] = {dw3v.x, dw3v.y, dw3v.z, dw3v.w};
  float p[4];
#pragma unroll
  for (int i = 0; i < 4; ++i) {
    float s = 0.f;
#pragma unroll
    for (int j = 0; j < 4; ++j) s = fmaf(frelu(acc2[i][j] + db2a[j]), dw3a[j], s);
    // reduce across the 16 tx lanes of this ty group
#pragma unroll
    for (int m = 1; m < 16; m <<= 1) s += __shfl_xor(s, m);
    p[i] = s;
  }
  if (tx == 0) {
    int l = l0 + ty * 4;
    if (l + 3 < L) {
      float b3 = db3[0];
      float4 o = make_float4(p[0] + b3, p[1] + b3, p[2] + b3, p[3] + b3);
      *(float4*)&out[l] = o;
    } else {
      for (int i = 0; i < 4; ++i)
        if (l + i < L) out[l + i] = p[i] + db3[0];
    }
  }
}

extern "C" void kernel_launch(void* const* d_in, const int* in_sizes, int n_in,
                              void* d_out, int out_size, void* d_ws, size_t ws_size,
                              hipStream_t stream) {
  const float* x = (const float*)d_in[0];
  const int* edge_index = (const int*)d_in[1];
  const float* ew = (const float*)d_in[2];
  const int* eli = (const int*)d_in[3];
  const float* w1 = (const float*)d_in[4];
  const float* b1 = (const float*)d_in[5];
  const float* w2 = (const float*)d_in[6];
  const float* b2 = (const float*)d_in[7];
  const float* w3 = (const float*)d_in[8];
  const float* b3 = (const float*)d_in[9];
  const float* w4 = (const float*)d_in[10];
  const float* b4 = (const float*)d_in[11];
  const float* bn_gamma = (const float*)d_in[12];
  const float* bn_beta = (const float*)d_in[13];
  const float* dw1 = (const float*)d_in[14];
  const float* db1 = (const float*)d_in[15];
  const float* dw2 = (const float*)d_in[16];
  const float* db2 = (const float*)d_in[17];
  const float* dw3 = (const float*)d_in[18];
  const float* db3 = (const float*)d_in[19];

  const int n = in_sizes[0] / 32;
  const int E = in_sizes[2];
  const int L = out_size;
  const int* rowv = edge_index;      // edge_index[0]
  const int* colv = edge_index + E;  // edge_index[1]

  char* ws = (char*)d_ws;
  size_t off = 0;
  float* bufA = (float*)(ws + off); off += (size_t)n * 128 * 4;
  float* bufB = (float*)(ws + off); off += (size_t)n * 128 * 4;
  float* dinv = (float*)(ws + off); off += (size_t)n * 4;
  int* hist = (int*)(ws + off);     off += (size_t)n * 4;
  int* indptr = (int*)(ws + off);   off += (size_t)(n + 1) * 4;
  off = (off + 255) & ~(size_t)255;
  int* rank = (int*)(ws + off);     off += (size_t)E * 4;
  off = (off + 255) & ~(size_t)255;
  float2* sedge = (float2*)(ws + off); off += (size_t)E * 8;
  off = (off + 255) & ~(size_t)255;
  double* bnpart = (double*)(ws + off); off += (size_t)BN_BLOCKS * 256 * 8;
  float2* bnss = (float2*)(ws + off);   off += 128 * 8;

  int eblocks = (E + 255) / 256;
  int nblocks = (n + 255) / 256;

  // ---- CSR build (single atomic pass) ----
  hipMemsetAsync(hist, 0, (size_t)n * 4, stream);
  hist_rank_kernel<<<eblocks, 256, 0, stream>>>(colv, hist, rank, E);
  scan_kernel<<<1, 1024, 0, stream>>>(hist, indptr, n);
  scatter_kernel<<<eblocks, 256, 0, stream>>>(rowv, colv, ew, indptr, rank, sedge, E);
  deg_dinv_kernel<<<nblocks, 256, 0, stream>>>(sedge, indptr, dinv, n);
  edgew_kernel<<<eblocks, 256, 0, stream>>>(sedge, dinv, E);

  dim3 gemm_grid128((n + 63) / 64, 2);
  dim3 gemm_grid64((n + 63) / 64, 1);
  int agg_blocks = (n * 64 + 255) / 256;
  int agg32_blocks = (n * 32 + 255) / 256;

  // ---- layer 1: agg x (32-dim) FIRST, then GEMM 32->128 (+b1); BN stats ----
  agg32_kernel<<<agg32_blocks, 256, 0, stream>>>(x, indptr, sedge, dinv, bufA, n);
  gemm_kernel<32><<<gemm_grid128, 256, 0, stream>>>(bufA, w1, bufB, n, 128, nullptr, b1);
  bn_part_kernel<<<BN_BLOCKS, 256, 0, stream>>>(bufB, bnpart, n);
  bn_reduce_finalize_kernel<<<128, 256, 0, stream>>>(bnpart, bn_gamma, bn_beta, bnss, n,
                                                     BN_BLOCKS);

  // ---- layer 2 (BN1+ReLU fused into A-staging) ----
  gemm_kernel<128><<<gemm_grid128, 256, 0, stream>>>(bufB, w2, bufA, n, 128, bnss, nullptr);
  agg_kernel<128><<<agg_blocks, 256, 0, stream>>>(bufA, indptr, sedge, dinv, b2, bufB, n);
  bn_part_kernel<<<BN_BLOCKS, 256, 0, stream>>>(bufB, bnpart, n);
  bn_reduce_finalize_kernel<<<128, 256, 0, stream>>>(bnpart, bn_gamma + 128, bn_beta + 128, bnss,
                                                     n, BN_BLOCKS);

  // ---- layer 3 ----
  gemm_kernel<128><<<gemm_grid128, 256, 0, stream>>>(bufB, w3, bufA, n, 128, bnss, nullptr);
  agg_kernel<128><<<agg_blocks, 256, 0, stream>>>(bufA, indptr, sedge, dinv, b3, bufB, n);
  bn_part_kernel<<<BN_BLOCKS, 256, 0, stream>>>(bufB, bnpart, n);
  bn_reduce_finalize_kernel<<<128, 256, 0, stream>>>(bnpart, bn_gamma + 256, bn_beta + 256, bnss,
                                                     n, BN_BLOCKS);

  // ---- layer 4: enc = conv(relu(bn3(h3)), w4, b4)  [n,64] ----
  gemm_kernel<128><<<gemm_grid64, 256, 0, stream>>>(bufB, w4, bufA, n, 64, bnss, nullptr);
  agg_kernel<64><<<agg_blocks, 256, 0, stream>>>(bufA, indptr, sedge, dinv, b4, bufB, n);

  // ---- decoder: P = [enc@dw1_top | enc@dw1_bot] -> fused per-edge MLP ----
  pre_gemm_kernel<<<dim3((n + 63) / 64, 2), 256, 0, stream>>>(bufB, dw1, bufA, n);
  decoder_kernel<<<(L + 63) / 64, 256, 0, stream>>>(bufA, eli, L, db1, dw2, db2, dw3, db3,
                                                    (float*)d_out);
}